// Round 4
// baseline (213.891 us; speedup 1.0000x reference)
//
#include <hip/hip_runtime.h>

#define NB 4
#define NC 128
#define NH 184
#define NW 320
#define TW 64
#define NJ 80
#define ND 9
#define HWPIX (NH * NW)                           // 58880, divisible by 256
#define NPIX (NB * NH * NW)                       // 235520 pixels per tensor
#define ZOFF ((size_t)2 * NPIX * NC)              // zero page offset (shorts)
#define WS_NEEDED (ZOFF * 2 + 512)                // 120.6 MB bf16 + zero page

typedef __attribute__((ext_vector_type(8))) short bf16x8;
typedef __attribute__((ext_vector_type(4))) float f32x4;
typedef __attribute__((ext_vector_type(4))) int   i32x4;

__device__ __forceinline__ unsigned short f2bf(float f) {
  unsigned int u = __float_as_uint(f);
  u = u + 0x7fffu + ((u >> 16) & 1u);             // RNE
  return (unsigned short)(u >> 16);
}

// ========== K1: normalize + CHW->HWC + fp32->bf16, float4 loads (1KB/instr) ==========
__global__ __launch_bounds__(256) void normalize_hwc(const float* __restrict__ f1,
                                                     const float* __restrict__ f2,
                                                     unsigned short* __restrict__ fn) {
  const int t  = threadIdx.x;
  const int pg = t & 63;                  // pixel-quad within block
  const int cg = t >> 6;                  // channel group [cg*32, cg*32+32)
  const int tensor = blockIdx.y;
  const float* src = tensor ? f2 : f1;
  unsigned short* dst = fn + (tensor ? (size_t)NPIX * NC : 0);

  const int p0  = blockIdx.x * 256;       // flat pixel base; b uniform in block
  const int b   = blockIdx.x / 230;       // 230 blocks per image (58880/256)
  const int hw0 = (blockIdx.x - b * 230) * 256;

  __shared__ f32x4 scr4[4][64];

  const float* sp = src + ((size_t)b * NC + cg * 32) * HWPIX + hw0 + pg * 4;
  f32x4 v[32];
  f32x4 ssv = {0.f, 0.f, 0.f, 0.f};
  #pragma unroll
  for (int i = 0; i < 32; ++i) {          // 64 lanes x 16B = 1KB coalesced
    v[i] = *reinterpret_cast<const f32x4*>(sp + (size_t)i * HWPIX);
    ssv += v[i] * v[i];
  }
  scr4[cg][pg] = ssv;
  __syncthreads();
  f32x4 s4 = scr4[0][pg] + scr4[1][pg] + scr4[2][pg] + scr4[3][pg];
  float inv[4];
  #pragma unroll
  for (int px = 0; px < 4; ++px) inv[px] = 1.f / fmaxf(sqrtf(s4[px]), 1e-12f);

  unsigned short* dp = dst + ((size_t)p0 + pg * 4) * NC + cg * 32;
  #pragma unroll
  for (int px = 0; px < 4; ++px) {
    #pragma unroll
    for (int k = 0; k < 4; ++k) {
      bf16x8 sv;
      #pragma unroll
      for (int j = 0; j < 8; ++j) sv[j] = (short)f2bf(v[k * 8 + j][px] * inv[px]);
      *reinterpret_cast<bf16x8*>(dp + (size_t)px * NC + k * 8) = sv;
    }
  }
  // zero page for K2's OOB loads (K1 completes before K2 on the same stream)
  if (blockIdx.x == 0 && tensor == 0 && t < 128) fn[ZOFF + t] = 0;
}

// ========== K2: banded MFMA, 24 loads in flight per chunk, branchless OOB ==========
__global__ __launch_bounds__(256) void corr_hwc(const unsigned short* __restrict__ fn,
                                                float* __restrict__ out) {
  // bijective XCD swizzle: 3680 = 8*460; contiguous h-runs per XCD
  const int bid = blockIdx.x;
  const int swz = (bid & 7) * 460 + (bid >> 3);
  const int wt = swz % 5;
  const int h  = (swz / 5) % NH;
  const int b  = swz / (5 * NH);
  const int w0 = wt * TW;

  const int t = threadIdx.x;
  const int lane = t & 63;
  const int wave = t >> 6;
  const int q = lane >> 4;
  const int n = lane & 15;

  const unsigned short* f1n = fn;
  const unsigned short* f2n = fn + (size_t)NPIX * NC;
  const unsigned short* zpage = fn + ZOFF;

  __shared__ float out_s[27][65];

  // A fragments: loaded once, reused for all 81 displacements
  const unsigned short* arow = f1n + ((size_t)(b * NH + h) * NW + w0 + wave * 16 + n) * NC;
  bf16x8 av[4];
  #pragma unroll
  for (int kk = 0; kk < 4; ++kk)
    av[kk] = *reinterpret_cast<const bf16x8*>(arow + kk * 32 + q * 8);

  const int j0 = w0 + wave * 16 - 4 + n;        // N-tile 0 col (may be <0)
  const int j1 = j0 + 16;                       // N-tile 1 col (may be >=NW)
  const bool j0ok = (j0 >= 0);                  // j0 <= 315 always
  const bool j1ok = (j1 < NW);                  // j1 >= 12 always

  #pragma unroll
  for (int chunk = 0; chunk < 3; ++chunk) {
    // ---- issue ALL 24 B-fragment loads for this chunk ----
    i32x4 bv[3][2][4];
    #pragma unroll
    for (int dd = 0; dd < 3; ++dd) {
      const int dyi = chunk * 3 + dd;
      const int hr = h + 4 - dyi;               // h - dy (ref: f2[h-dy, w-dx])
      const bool rok = (hr >= 0) && (hr < NH);
      const size_t rb = (size_t)(b * NH + (rok ? hr : 0)) * NW * NC;
      const unsigned short* bp0 = (rok && j0ok) ? (f2n + rb + (size_t)(j0 << 7)) : zpage;
      const unsigned short* bp1 = (rok && j1ok) ? (f2n + rb + (size_t)(j1 << 7)) : zpage;
      #pragma unroll
      for (int kk = 0; kk < 4; ++kk)
        bv[dd][0][kk] = *reinterpret_cast<const i32x4*>(bp0 + kk * 32 + q * 8);
      #pragma unroll
      for (int kk = 0; kk < 4; ++kk)
        bv[dd][1][kk] = *reinterpret_cast<const i32x4*>(bp1 + kk * 32 + q * 8);
    }

    f32x4 acc[3][2];
    #pragma unroll
    for (int dd = 0; dd < 3; ++dd)
      #pragma unroll
      for (int T = 0; T < 2; ++T)
        acc[dd][T] = (f32x4){0.f, 0.f, 0.f, 0.f};

    // ---- MFMAs (loads drain under these) ----
    #pragma unroll
    for (int dd = 0; dd < 3; ++dd)
      #pragma unroll
      for (int T = 0; T < 2; ++T)
        #pragma unroll
        for (int kk = 0; kk < 4; ++kk)
          acc[dd][T] = __builtin_amdgcn_mfma_f32_16x16x32_bf16(
              av[kk], __builtin_bit_cast(bf16x8, bv[dd][T][kk]), acc[dd][T], 0, 0, 0);

    __syncthreads();                            // prev chunk's out_s readers done
    // D elem (reg r): w-local = wave*16+q*4+r; dx = w - j = q*4+r+4-T*16-n
    #pragma unroll
    for (int dd = 0; dd < 3; ++dd)
      #pragma unroll
      for (int T = 0; T < 2; ++T)
        #pragma unroll
        for (int r = 0; r < 4; ++r) {
          const int wl = wave * 16 + q * 4 + r;
          const int dx = q * 4 + r + 4 - T * 16 - n;
          if (dx >= -4 && dx <= 4)
            out_s[dd * 9 + dx + 4][wl] = acc[dd][T][r];
        }
    __syncthreads();
    #pragma unroll
    for (int kidx = 0; kidx < 7; ++kidx) {
      const int k = kidx * 256 + t;
      if (k < 27 * 64) {
        const int dl = k >> 6;
        const int wl = k & 63;
        out[(((size_t)b * 81 + chunk * 27 + dl) * NH + h) * NW + w0 + wl] = out_s[dl][wl];
      }
    }
  }
}

// ========== fallback: round-2 fused kernel (used if ws too small) ==========
__global__ __launch_bounds__(256) void corr_mfma(const float* __restrict__ f1,
                                                 const float* __restrict__ f2,
                                                 float* __restrict__ out) {
  const int wt = blockIdx.x;
  const int h  = blockIdx.y;
  const int b  = blockIdx.z;
  const int w0 = wt * TW;
  const int t  = threadIdx.x;
  const int lane = t & 63;
  const int wave = t >> 6;

  __shared__ __align__(16) unsigned short a_s[TW * NC];
  __shared__ __align__(16) unsigned short b_s[NJ * NC];
  __shared__ float scr[NJ][17];
  __shared__ float invn1_s[TW];
  __shared__ float invn2_s[NJ];
  __shared__ float out_s[ND][TW];

  const size_t HW = (size_t)NH * NW;

  {
    const int w  = t & 63;
    const int cg = t >> 6;
    float ss = 0.f;
    #pragma unroll
    for (int cc = 0; cc < 4; ++cc) {
      const int cb = cg * 32 + cc * 8;
      const float* p = f1 + ((size_t)b * NC + cb) * HW + (size_t)h * NW + w0 + w;
      float v[8];
      #pragma unroll
      for (int i = 0; i < 8; ++i) v[i] = p[i * HW];
      bf16x8 sv;
      #pragma unroll
      for (int i = 0; i < 8; ++i) {
        unsigned int u = __float_as_uint(v[i]);
        u = (u + 0x7fffu + ((u >> 16) & 1u)) & 0xffff0000u;
        float vb = __uint_as_float(u);
        ss += vb * vb;
        sv[i] = (short)(u >> 16);
      }
      const int idx = (w * NC + cb) ^ ((w & 7) << 3);
      *reinterpret_cast<bf16x8*>(&a_s[idx]) = sv;
    }
    scr[w][cg] = ss;
  }
  __syncthreads();
  if (t < TW) {
    float s = scr[t][0] + scr[t][1] + scr[t][2] + scr[t][3];
    invn1_s[t] = 1.f / fmaxf(sqrtf(s), 1e-12f);
  }

  for (int dyi = 0; dyi < ND; ++dyi) {
    __syncthreads();
    const int hr = h + 4 - dyi;
    {
      const int jl16 = t & 15;
      const int cg   = t >> 4;
      const int cb   = cg * 8;
      const bool rowok = (hr >= 0) && (hr < NH);
      #pragma unroll
      for (int s5 = 0; s5 < 5; ++s5) {
        const int jl = s5 * 16 + jl16;
        const int jg = w0 - 4 + jl;
        float v[8];
        if (rowok && jg >= 0 && jg < NW) {
          const float* p = f2 + ((size_t)b * NC + cb) * HW + (size_t)hr * NW + jg;
          #pragma unroll
          for (int i = 0; i < 8; ++i) v[i] = p[i * HW];
        } else {
          #pragma unroll
          for (int i = 0; i < 8; ++i) v[i] = 0.f;
        }
        float ss = 0.f;
        bf16x8 sv;
        #pragma unroll
        for (int i = 0; i < 8; ++i) {
          unsigned int u = __float_as_uint(v[i]);
          u = (u + 0x7fffu + ((u >> 16) & 1u)) & 0xffff0000u;
          float vb = __uint_as_float(u);
          ss += vb * vb;
          sv[i] = (short)(u >> 16);
        }
        const int idx = (jl * NC + cb) ^ ((jl & 7) << 3);
        *reinterpret_cast<bf16x8*>(&b_s[idx]) = sv;
        scr[jl][cg] = ss;
      }
    }
    __syncthreads();
    if (t < NJ) {
      float s = 0.f;
      #pragma unroll
      for (int i = 0; i < 16; ++i) s += scr[t][i];
      invn2_s[t] = 1.f / fmaxf(sqrtf(s), 1e-12f);
    }
    __syncthreads();
    {
      const int m = wave;
      const int q = lane >> 4;
      const int n = lane & 15;
      f32x4 acc0 = {0.f, 0.f, 0.f, 0.f};
      f32x4 acc1 = {0.f, 0.f, 0.f, 0.f};
      const int wl  = m * 16 + n;
      const int jl0 = m * 16 + n;
      const int jl1 = m * 16 + 16 + n;
      #pragma unroll
      for (int kk = 0; kk < 4; ++kk) {
        const int c0 = kk * 32 + q * 8;
        bf16x8 av  = *reinterpret_cast<const bf16x8*>(&a_s[(wl  * NC + c0) ^ ((wl  & 7) << 3)]);
        bf16x8 bv0 = *reinterpret_cast<const bf16x8*>(&b_s[(jl0 * NC + c0) ^ ((jl0 & 7) << 3)]);
        bf16x8 bv1 = *reinterpret_cast<const bf16x8*>(&b_s[(jl1 * NC + c0) ^ ((jl1 & 7) << 3)]);
        acc0 = __builtin_amdgcn_mfma_f32_16x16x32_bf16(av, bv0, acc0, 0, 0, 0);
        acc1 = __builtin_amdgcn_mfma_f32_16x16x32_bf16(av, bv1, acc1, 0, 0, 0);
      }
      #pragma unroll
      for (int T = 0; T < 2; ++T) {
        const f32x4 a = T ? acc1 : acc0;
        const int jl = m * 16 + T * 16 + n;
        const float i2 = invn2_s[jl];
        #pragma unroll
        for (int r = 0; r < 4; ++r) {
          const int wr = m * 16 + q * 4 + r;
          const int dx = wr + 4 - jl;
          if (dx >= -4 && dx <= 4) {
            out_s[dx + 4][wr] = a[r] * invn1_s[wr] * i2;
          }
        }
      }
    }
    __syncthreads();
    #pragma unroll
    for (int kidx = 0; kidx < 3; ++kidx) {
      const int k = kidx * 256 + t;
      if (k < ND * TW) {
        const int dx = k >> 6;
        const int wl = k & 63;
        const int d  = dyi * ND + dx;
        out[(((size_t)b * 81 + d) * NH + h) * NW + w0 + wl] = out_s[dx][wl];
      }
    }
  }
}

extern "C" void kernel_launch(void* const* d_in, const int* in_sizes, int n_in,
                              void* d_out, int out_size, void* d_ws, size_t ws_size,
                              hipStream_t stream) {
  const float* f1 = (const float*)d_in[0];
  const float* f2 = (const float*)d_in[1];
  float* out = (float*)d_out;
  if (d_ws != nullptr && ws_size >= WS_NEEDED) {
    unsigned short* fn = (unsigned short*)d_ws;
    normalize_hwc<<<dim3(NPIX / 256, 2), 256, 0, stream>>>(f1, f2, fn);
    corr_hwc<<<dim3(NW / TW * NH * NB), 256, 0, stream>>>(fn, out);
  } else {
    corr_mfma<<<dim3(NW / TW, NH, NB), 256, 0, stream>>>(f1, f2, out);
  }
}

// Round 5
// 212.595 us; speedup vs baseline: 1.0061x; 1.0061x over previous
//
#include <hip/hip_runtime.h>

#define NB 4
#define NC 128
#define NH 184
#define NW 320
#define TW 64
#define NJ 80
#define ND 9
#define HWPIX (NH * NW)                           // 58880, divisible by 256
#define NPIX (NB * NH * NW)                       // 235520 pixels per tensor
#define ZOFF ((size_t)2 * NPIX * NC)              // zero page offset (shorts)
#define WS_NEEDED (ZOFF * 2 + 512)                // 120.6 MB bf16 + zero page

typedef __attribute__((ext_vector_type(8))) short bf16x8;
typedef __attribute__((ext_vector_type(4))) float f32x4;
typedef __attribute__((ext_vector_type(4))) int   i32x4;

__device__ __forceinline__ unsigned short f2bf(float f) {
  unsigned int u = __float_as_uint(f);
  u = u + 0x7fffu + ((u >> 16) & 1u);             // RNE
  return (unsigned short)(u >> 16);
}

// ========== K1: normalize + CHW->HWC + fp32->bf16, float4 loads (1KB/instr) ==========
__global__ __launch_bounds__(256) void normalize_hwc(const float* __restrict__ f1,
                                                     const float* __restrict__ f2,
                                                     unsigned short* __restrict__ fn) {
  const int t  = threadIdx.x;
  const int pg = t & 63;                  // pixel-quad within block
  const int cg = t >> 6;                  // channel group [cg*32, cg*32+32)
  const int tensor = blockIdx.y;
  const float* src = tensor ? f2 : f1;
  unsigned short* dst = fn + (tensor ? (size_t)NPIX * NC : 0);

  const int p0  = blockIdx.x * 256;       // flat pixel base; b uniform in block
  const int b   = blockIdx.x / 230;       // 230 blocks per image (58880/256)
  const int hw0 = (blockIdx.x - b * 230) * 256;

  __shared__ f32x4 scr4[4][64];

  const float* sp = src + ((size_t)b * NC + cg * 32) * HWPIX + hw0 + pg * 4;
  f32x4 v[32];
  f32x4 ssv = {0.f, 0.f, 0.f, 0.f};
  #pragma unroll
  for (int i = 0; i < 32; ++i) {          // 64 lanes x 16B = 1KB coalesced
    v[i] = *reinterpret_cast<const f32x4*>(sp + (size_t)i * HWPIX);
    ssv += v[i] * v[i];
  }
  scr4[cg][pg] = ssv;
  __syncthreads();
  f32x4 s4 = scr4[0][pg] + scr4[1][pg] + scr4[2][pg] + scr4[3][pg];
  float inv[4];
  #pragma unroll
  for (int px = 0; px < 4; ++px) inv[px] = 1.f / fmaxf(sqrtf(s4[px]), 1e-12f);

  unsigned short* dp = dst + ((size_t)p0 + pg * 4) * NC + cg * 32;
  #pragma unroll
  for (int px = 0; px < 4; ++px) {
    #pragma unroll
    for (int k = 0; k < 4; ++k) {
      bf16x8 sv;
      #pragma unroll
      for (int j = 0; j < 8; ++j) sv[j] = (short)f2bf(v[k * 8 + j][px] * inv[px]);
      *reinterpret_cast<bf16x8*>(dp + (size_t)px * NC + k * 8) = sv;
    }
  }
  // zero page for K2's OOB loads (K1 completes before K2 on the same stream)
  if (blockIdx.x == 0 && tensor == 0 && t < 128) fn[ZOFF + t] = 0;
}

// ========== K2: banded MFMA; 24-load batch pinned ahead of MFMAs ==========
__global__ __launch_bounds__(256) void corr_hwc(const unsigned short* __restrict__ fn,
                                                float* __restrict__ out) {
  // bijective XCD swizzle: 3680 = 8*460; contiguous h-runs per XCD
  const int bid = blockIdx.x;
  const int swz = (bid & 7) * 460 + (bid >> 3);
  const int wt = swz % 5;
  const int h  = (swz / 5) % NH;
  const int b  = swz / (5 * NH);
  const int w0 = wt * TW;

  const int t = threadIdx.x;
  const int lane = t & 63;
  const int wave = t >> 6;
  const int q = lane >> 4;
  const int n = lane & 15;

  const unsigned short* f1n = fn;
  const unsigned short* f2n = fn + (size_t)NPIX * NC;
  const unsigned short* zpage = fn + ZOFF;

  __shared__ float out_s[27][65];

  // A fragments: loaded once, reused for all 81 displacements
  const unsigned short* arow = f1n + ((size_t)(b * NH + h) * NW + w0 + wave * 16 + n) * NC;
  bf16x8 av[4];
  #pragma unroll
  for (int kk = 0; kk < 4; ++kk)
    av[kk] = *reinterpret_cast<const bf16x8*>(arow + kk * 32 + q * 8);

  const int j0 = w0 + wave * 16 - 4 + n;        // N-tile 0 col (may be <0)
  const int j1 = j0 + 16;                       // N-tile 1 col (may be >=NW)
  const bool j0ok = (j0 >= 0);                  // j0 <= 315 always
  const bool j1ok = (j1 < NW);                  // j1 >= 12 always

  #pragma unroll
  for (int chunk = 0; chunk < 3; ++chunk) {
    // ---- issue ALL 24 B-fragment loads for this chunk ----
    i32x4 bv[3][2][4];
    #pragma unroll
    for (int dd = 0; dd < 3; ++dd) {
      const int dyi = chunk * 3 + dd;
      const int hr = h + 4 - dyi;               // h - dy (ref: f2[h-dy, w-dx])
      const bool rok = (hr >= 0) && (hr < NH);
      const size_t rb = (size_t)(b * NH + (rok ? hr : 0)) * NW * NC;
      const unsigned short* bp0 = (rok && j0ok) ? (f2n + rb + (size_t)(j0 << 7)) : zpage;
      const unsigned short* bp1 = (rok && j1ok) ? (f2n + rb + (size_t)(j1 << 7)) : zpage;
      #pragma unroll
      for (int kk = 0; kk < 4; ++kk)
        bv[dd][0][kk] = *reinterpret_cast<const i32x4*>(bp0 + kk * 32 + q * 8);
      #pragma unroll
      for (int kk = 0; kk < 4; ++kk)
        bv[dd][1][kk] = *reinterpret_cast<const i32x4*>(bp1 + kk * 32 + q * 8);
    }

    // pin: no MFMA may move above, no load may sink below (rule #18/#19:
    // the compiler otherwise re-sinks loads next to uses — R4 showed VGPR=56)
    __builtin_amdgcn_sched_barrier(0);

    f32x4 acc[3][2];
    #pragma unroll
    for (int dd = 0; dd < 3; ++dd)
      #pragma unroll
      for (int T = 0; T < 2; ++T)
        acc[dd][T] = (f32x4){0.f, 0.f, 0.f, 0.f};

    // ---- MFMAs (one counted-vmcnt wall, then 24 back-to-back) ----
    #pragma unroll
    for (int dd = 0; dd < 3; ++dd)
      #pragma unroll
      for (int T = 0; T < 2; ++T)
        #pragma unroll
        for (int kk = 0; kk < 4; ++kk)
          acc[dd][T] = __builtin_amdgcn_mfma_f32_16x16x32_bf16(
              av[kk], __builtin_bit_cast(bf16x8, bv[dd][T][kk]), acc[dd][T], 0, 0, 0);

    __syncthreads();                            // prev chunk's out_s readers done
    // D elem (reg r): w-local = wave*16+q*4+r; dx = w - j = q*4+r+4-T*16-n
    #pragma unroll
    for (int dd = 0; dd < 3; ++dd)
      #pragma unroll
      for (int T = 0; T < 2; ++T)
        #pragma unroll
        for (int r = 0; r < 4; ++r) {
          const int wl = wave * 16 + q * 4 + r;
          const int dx = q * 4 + r + 4 - T * 16 - n;
          if (dx >= -4 && dx <= 4)
            out_s[dd * 9 + dx + 4][wl] = acc[dd][T][r];
        }
    __syncthreads();
    #pragma unroll
    for (int kidx = 0; kidx < 7; ++kidx) {
      const int k = kidx * 256 + t;
      if (k < 27 * 64) {
        const int dl = k >> 6;
        const int wl = k & 63;
        out[(((size_t)b * 81 + chunk * 27 + dl) * NH + h) * NW + w0 + wl] = out_s[dl][wl];
      }
    }
  }
}

// ========== fallback: round-2 fused kernel (used if ws too small) ==========
__global__ __launch_bounds__(256) void corr_mfma(const float* __restrict__ f1,
                                                 const float* __restrict__ f2,
                                                 float* __restrict__ out) {
  const int wt = blockIdx.x;
  const int h  = blockIdx.y;
  const int b  = blockIdx.z;
  const int w0 = wt * TW;
  const int t  = threadIdx.x;
  const int lane = t & 63;
  const int wave = t >> 6;

  __shared__ __align__(16) unsigned short a_s[TW * NC];
  __shared__ __align__(16) unsigned short b_s[NJ * NC];
  __shared__ float scr[NJ][17];
  __shared__ float invn1_s[TW];
  __shared__ float invn2_s[NJ];
  __shared__ float out_s[ND][TW];

  const size_t HW = (size_t)NH * NW;

  {
    const int w  = t & 63;
    const int cg = t >> 6;
    float ss = 0.f;
    #pragma unroll
    for (int cc = 0; cc < 4; ++cc) {
      const int cb = cg * 32 + cc * 8;
      const float* p = f1 + ((size_t)b * NC + cb) * HW + (size_t)h * NW + w0 + w;
      float v[8];
      #pragma unroll
      for (int i = 0; i < 8; ++i) v[i] = p[i * HW];
      bf16x8 sv;
      #pragma unroll
      for (int i = 0; i < 8; ++i) {
        unsigned int u = __float_as_uint(v[i]);
        u = (u + 0x7fffu + ((u >> 16) & 1u)) & 0xffff0000u;
        float vb = __uint_as_float(u);
        ss += vb * vb;
        sv[i] = (short)(u >> 16);
      }
      const int idx = (w * NC + cb) ^ ((w & 7) << 3);
      *reinterpret_cast<bf16x8*>(&a_s[idx]) = sv;
    }
    scr[w][cg] = ss;
  }
  __syncthreads();
  if (t < TW) {
    float s = scr[t][0] + scr[t][1] + scr[t][2] + scr[t][3];
    invn1_s[t] = 1.f / fmaxf(sqrtf(s), 1e-12f);
  }

  for (int dyi = 0; dyi < ND; ++dyi) {
    __syncthreads();
    const int hr = h + 4 - dyi;
    {
      const int jl16 = t & 15;
      const int cg   = t >> 4;
      const int cb   = cg * 8;
      const bool rowok = (hr >= 0) && (hr < NH);
      #pragma unroll
      for (int s5 = 0; s5 < 5; ++s5) {
        const int jl = s5 * 16 + jl16;
        const int jg = w0 - 4 + jl;
        float v[8];
        if (rowok && jg >= 0 && jg < NW) {
          const float* p = f2 + ((size_t)b * NC + cb) * HW + (size_t)hr * NW + jg;
          #pragma unroll
          for (int i = 0; i < 8; ++i) v[i] = p[i * HW];
        } else {
          #pragma unroll
          for (int i = 0; i < 8; ++i) v[i] = 0.f;
        }
        float ss = 0.f;
        bf16x8 sv;
        #pragma unroll
        for (int i = 0; i < 8; ++i) {
          unsigned int u = __float_as_uint(v[i]);
          u = (u + 0x7fffu + ((u >> 16) & 1u)) & 0xffff0000u;
          float vb = __uint_as_float(u);
          ss += vb * vb;
          sv[i] = (short)(u >> 16);
        }
        const int idx = (jl * NC + cb) ^ ((jl & 7) << 3);
        *reinterpret_cast<bf16x8*>(&b_s[idx]) = sv;
        scr[jl][cg] = ss;
      }
    }
    __syncthreads();
    if (t < NJ) {
      float s = 0.f;
      #pragma unroll
      for (int i = 0; i < 16; ++i) s += scr[t][i];
      invn2_s[t] = 1.f / fmaxf(sqrtf(s), 1e-12f);
    }
    __syncthreads();
    {
      const int m = wave;
      const int q = lane >> 4;
      const int n = lane & 15;
      f32x4 acc0 = {0.f, 0.f, 0.f, 0.f};
      f32x4 acc1 = {0.f, 0.f, 0.f, 0.f};
      const int wl  = m * 16 + n;
      const int jl0 = m * 16 + n;
      const int jl1 = m * 16 + 16 + n;
      #pragma unroll
      for (int kk = 0; kk < 4; ++kk) {
        const int c0 = kk * 32 + q * 8;
        bf16x8 av  = *reinterpret_cast<const bf16x8*>(&a_s[(wl  * NC + c0) ^ ((wl  & 7) << 3)]);
        bf16x8 bv0 = *reinterpret_cast<const bf16x8*>(&b_s[(jl0 * NC + c0) ^ ((jl0 & 7) << 3)]);
        bf16x8 bv1 = *reinterpret_cast<const bf16x8*>(&b_s[(jl1 * NC + c0) ^ ((jl1 & 7) << 3)]);
        acc0 = __builtin_amdgcn_mfma_f32_16x16x32_bf16(av, bv0, acc0, 0, 0, 0);
        acc1 = __builtin_amdgcn_mfma_f32_16x16x32_bf16(av, bv1, acc1, 0, 0, 0);
      }
      #pragma unroll
      for (int T = 0; T < 2; ++T) {
        const f32x4 a = T ? acc1 : acc0;
        const int jl = m * 16 + T * 16 + n;
        const float i2 = invn2_s[jl];
        #pragma unroll
        for (int r = 0; r < 4; ++r) {
          const int wr = m * 16 + q * 4 + r;
          const int dx = wr + 4 - jl;
          if (dx >= -4 && dx <= 4) {
            out_s[dx + 4][wr] = a[r] * invn1_s[wr] * i2;
          }
        }
      }
    }
    __syncthreads();
    #pragma unroll
    for (int kidx = 0; kidx < 3; ++kidx) {
      const int k = kidx * 256 + t;
      if (k < ND * TW) {
        const int dx = k >> 6;
        const int wl = k & 63;
        const int d  = dyi * ND + dx;
        out[(((size_t)b * 81 + d) * NH + h) * NW + w0 + wl] = out_s[dx][wl];
      }
    }
  }
}

extern "C" void kernel_launch(void* const* d_in, const int* in_sizes, int n_in,
                              void* d_out, int out_size, void* d_ws, size_t ws_size,
                              hipStream_t stream) {
  const float* f1 = (const float*)d_in[0];
  const float* f2 = (const float*)d_in[1];
  float* out = (float*)d_out;
  if (d_ws != nullptr && ws_size >= WS_NEEDED) {
    unsigned short* fn = (unsigned short*)d_ws;
    normalize_hwc<<<dim3(NPIX / 256, 2), 256, 0, stream>>>(f1, f2, fn);
    corr_hwc<<<dim3(NW / TW * NH * NB), 256, 0, stream>>>(fn, out);
  } else {
    corr_mfma<<<dim3(NW / TW, NH, NB), 256, 0, stream>>>(f1, f2, out);
  }
}

// Round 6
// 143.476 us; speedup vs baseline: 1.4908x; 1.4817x over previous
//
#include <hip/hip_runtime.h>

#define NB 4
#define NC 128
#define NH 184
#define NW 320
#define TH 8                                      // output h-rows per block (184=23*8)
#define TWB 32                                    // output w-cols per block (320=10*32)
#define HWPIX (NH * NW)                           // 58880
#define NPIX (NB * NH * NW)                       // 235520 pixels per tensor
#define ZOFF ((size_t)2 * NPIX * NC)              // zero page offset (shorts)
#define WS_NEEDED (ZOFF * 2 + 512)                // 120.6 MB bf16 + zero page

typedef __attribute__((ext_vector_type(8))) short bf16x8;
typedef __attribute__((ext_vector_type(4))) float f32x4;

__device__ __forceinline__ unsigned short f2bf(float f) {
  unsigned int u = __float_as_uint(f);
  u = u + 0x7fffu + ((u >> 16) & 1u);             // RNE
  return (unsigned short)(u >> 16);
}

// ========== K1: normalize + CHW->HWC + fp32->bf16, float4 loads ==========
__global__ __launch_bounds__(256) void normalize_hwc(const float* __restrict__ f1,
                                                     const float* __restrict__ f2,
                                                     unsigned short* __restrict__ fn) {
  const int t  = threadIdx.x;
  const int pg = t & 63;
  const int cg = t >> 6;
  const int tensor = blockIdx.y;
  const float* src = tensor ? f2 : f1;
  unsigned short* dst = fn + (tensor ? (size_t)NPIX * NC : 0);

  const int p0  = blockIdx.x * 256;
  const int b   = blockIdx.x / 230;               // 230 blocks per image
  const int hw0 = (blockIdx.x - b * 230) * 256;

  __shared__ f32x4 scr4[4][64];

  const float* sp = src + ((size_t)b * NC + cg * 32) * HWPIX + hw0 + pg * 4;
  f32x4 v[32];
  f32x4 ssv = {0.f, 0.f, 0.f, 0.f};
  #pragma unroll
  for (int i = 0; i < 32; ++i) {
    v[i] = *reinterpret_cast<const f32x4*>(sp + (size_t)i * HWPIX);
    ssv += v[i] * v[i];
  }
  scr4[cg][pg] = ssv;
  __syncthreads();
  f32x4 s4 = scr4[0][pg] + scr4[1][pg] + scr4[2][pg] + scr4[3][pg];
  float inv[4];
  #pragma unroll
  for (int px = 0; px < 4; ++px) inv[px] = 1.f / fmaxf(sqrtf(s4[px]), 1e-12f);

  unsigned short* dp = dst + ((size_t)p0 + pg * 4) * NC + cg * 32;
  #pragma unroll
  for (int px = 0; px < 4; ++px) {
    #pragma unroll
    for (int k = 0; k < 4; ++k) {
      bf16x8 sv;
      #pragma unroll
      for (int j = 0; j < 8; ++j) sv[j] = (short)f2bf(v[k * 8 + j][px] * inv[px]);
      *reinterpret_cast<bf16x8*>(dp + (size_t)px * NC + k * 8) = sv;
    }
  }
  if (blockIdx.x == 0 && tensor == 0 && t < 128) fn[ZOFF + t] = 0;
}

// ========== K2: vertical-tiled banded MFMA; f2 rows streamed once ==========
__global__ __launch_bounds__(128, 2) void corr_hwc2(const unsigned short* __restrict__ fn,
                                                    float* __restrict__ out) {
  // grid 920 = 8*115; ht-major so same-XCD neighbors share f2 rows in L2
  const int bid = blockIdx.x;
  const int swz = (bid & 7) * 115 + (bid >> 3);
  const int ht  = swz % 23;
  const int wtb = (swz / 23) % 10;
  const int b   = swz / 230;
  const int h0  = ht * TH;
  const int w0  = wtb * TWB;

  const int t = threadIdx.x;                      // 0..127 (2 waves)
  const int lane = t & 63;
  const int wv = t >> 6;                          // wave owns w in [wv*16, wv*16+16)
  const int q = lane >> 4;
  const int n = lane & 15;

  const unsigned short* f1n = fn;
  const unsigned short* f2n = fn + (size_t)NPIX * NC;
  const unsigned short* zpage = fn + ZOFF;

  __shared__ float out_s[2][9][17];               // per-wave transpose buffer

  // ---- A fragments: 8 rows x 4 kk, loaded once, reused for all 81 disps ----
  bf16x8 av[TH][4];
  #pragma unroll
  for (int hh = 0; hh < TH; ++hh) {
    const unsigned short* ap =
        f1n + ((size_t)(b * NH + h0 + hh) * NW + w0 + wv * 16 + n) * NC + q * 8;
    #pragma unroll
    for (int kk = 0; kk < 4; ++kk)
      av[hh][kk] = *reinterpret_cast<const bf16x8*>(ap + kk * 32);
  }

  const int j0 = w0 + wv * 16 - 4 + n;            // N-tile 0 col (may be <0)
  const int j1 = j0 + 16;                         // N-tile 1 col (may be >=NW)

  // ---- helpers (macros keep all register indices compile-time; rule #20) ----
  bf16x8 bA[2][4], bB[2][4];

#define LD_ROW(BUF, RR) do {                                                     \
    const int hr_ = h0 + (RR);                                                   \
    const bool rok_ = (hr_ >= 0) && (hr_ < NH);                                  \
    const size_t rb_ = (size_t)(b * NH + (rok_ ? hr_ : 0)) * NW * NC;            \
    const unsigned short* p0_ =                                                  \
        (rok_ && j0 >= 0) ? (f2n + rb_ + (size_t)j0 * NC + q * 8) : (zpage + q * 8); \
    const unsigned short* p1_ =                                                  \
        (rok_ && j1 < NW) ? (f2n + rb_ + (size_t)j1 * NC + q * 8) : (zpage + q * 8); \
    _Pragma("unroll")                                                            \
    for (int kk = 0; kk < 4; ++kk)                                               \
      BUF[0][kk] = *reinterpret_cast<const bf16x8*>(p0_ + kk * 32);              \
    _Pragma("unroll")                                                            \
    for (int kk = 0; kk < 4; ++kk)                                               \
      BUF[1][kk] = *reinterpret_cast<const bf16x8*>(p1_ + kk * 32);              \
  } while (0)

#define COMPUTE(BUF, RR) do {                                                    \
    _Pragma("unroll")                                                            \
    for (int hh = 0; hh < TH; ++hh) {                                            \
      const int dyi_ = hh - (RR) + 4;             /* dy+4; wave-uniform */       \
      if (dyi_ >= 0 && dyi_ <= 8) {                                              \
        f32x4 a0 = {0.f, 0.f, 0.f, 0.f};                                         \
        f32x4 a1 = {0.f, 0.f, 0.f, 0.f};                                         \
        _Pragma("unroll")                                                        \
        for (int kk = 0; kk < 4; ++kk) {                                         \
          a0 = __builtin_amdgcn_mfma_f32_16x16x32_bf16(av[hh][kk], BUF[0][kk], a0, 0, 0, 0); \
          a1 = __builtin_amdgcn_mfma_f32_16x16x32_bf16(av[hh][kk], BUF[1][kk], a1, 0, 0, 0); \
        }                                                                        \
        _Pragma("unroll")                                                        \
        for (int r = 0; r < 4; ++r) {            /* T=0: dxi = 4q+r+8-n  */      \
          const int dxi0 = 4 * q + r + 8 - n;                                    \
          if (dxi0 >= 0 && dxi0 <= 8) out_s[wv][dxi0][4 * q + r] = a0[r];        \
          const int dxi1 = 4 * q + r - 8 - n;    /* T=1 */                       \
          if (dxi1 >= 0 && dxi1 <= 8) out_s[wv][dxi1][4 * q + r] = a1[r];        \
        }                                                                        \
        _Pragma("unroll")                                                        \
        for (int i = 0; i < 3; ++i) {                                            \
          const int idx = i * 64 + lane;                                         \
          if (idx < 144) {                                                       \
            const int dx_ = idx >> 4;                                            \
            const int wc_ = idx & 15;                                            \
            out[((size_t)(b * 81 + dyi_ * 9 + dx_) * NH + (h0 + hh)) * NW        \
                + w0 + wv * 16 + wc_] = out_s[wv][dx_][wc_];                     \
          }                                                                      \
        }                                                                        \
      }                                                                          \
    }                                                                            \
  } while (0)

  // ---- main loop over 16 f2 rows (rr = hr - h0 in [-4, 11]), double-buffered ----
  LD_ROW(bA, -4);
  for (int k = 0; k < 7; ++k) {
    const int rr = 2 * k - 4;
    LD_ROW(bB, rr + 1);
    __builtin_amdgcn_sched_barrier(0);
    COMPUTE(bA, rr);
    LD_ROW(bA, rr + 2);
    __builtin_amdgcn_sched_barrier(0);
    COMPUTE(bB, rr + 1);
  }
  LD_ROW(bB, 11);
  __builtin_amdgcn_sched_barrier(0);
  COMPUTE(bA, 10);
  COMPUTE(bB, 11);

#undef LD_ROW
#undef COMPUTE
}

// ========== fallback: round-2 fused kernel (used if ws too small) ==========
__global__ __launch_bounds__(256) void corr_mfma(const float* __restrict__ f1,
                                                 const float* __restrict__ f2,
                                                 float* __restrict__ out) {
  const int wt = blockIdx.x;
  const int h  = blockIdx.y;
  const int b  = blockIdx.z;
  const int w0 = wt * 64;
  const int t  = threadIdx.x;
  const int lane = t & 63;
  const int wave = t >> 6;

  __shared__ __align__(16) unsigned short a_s[64 * NC];
  __shared__ __align__(16) unsigned short b_s[80 * NC];
  __shared__ float scr[80][17];
  __shared__ float invn1_s[64];
  __shared__ float invn2_s[80];
  __shared__ float out_s[9][64];

  const size_t HW = (size_t)NH * NW;

  {
    const int w  = t & 63;
    const int cg = t >> 6;
    float ss = 0.f;
    #pragma unroll
    for (int cc = 0; cc < 4; ++cc) {
      const int cb = cg * 32 + cc * 8;
      const float* p = f1 + ((size_t)b * NC + cb) * HW + (size_t)h * NW + w0 + w;
      float v[8];
      #pragma unroll
      for (int i = 0; i < 8; ++i) v[i] = p[i * HW];
      bf16x8 sv;
      #pragma unroll
      for (int i = 0; i < 8; ++i) {
        unsigned int u = __float_as_uint(v[i]);
        u = (u + 0x7fffu + ((u >> 16) & 1u)) & 0xffff0000u;
        float vb = __uint_as_float(u);
        ss += vb * vb;
        sv[i] = (short)(u >> 16);
      }
      const int idx = (w * NC + cb) ^ ((w & 7) << 3);
      *reinterpret_cast<bf16x8*>(&a_s[idx]) = sv;
    }
    scr[w][cg] = ss;
  }
  __syncthreads();
  if (t < 64) {
    float s = scr[t][0] + scr[t][1] + scr[t][2] + scr[t][3];
    invn1_s[t] = 1.f / fmaxf(sqrtf(s), 1e-12f);
  }

  for (int dyi = 0; dyi < 9; ++dyi) {
    __syncthreads();
    const int hr = h + 4 - dyi;
    {
      const int jl16 = t & 15;
      const int cg   = t >> 4;
      const int cb   = cg * 8;
      const bool rowok = (hr >= 0) && (hr < NH);
      #pragma unroll
      for (int s5 = 0; s5 < 5; ++s5) {
        const int jl = s5 * 16 + jl16;
        const int jg = w0 - 4 + jl;
        float v[8];
        if (rowok && jg >= 0 && jg < NW) {
          const float* p = f2 + ((size_t)b * NC + cb) * HW + (size_t)hr * NW + jg;
          #pragma unroll
          for (int i = 0; i < 8; ++i) v[i] = p[i * HW];
        } else {
          #pragma unroll
          for (int i = 0; i < 8; ++i) v[i] = 0.f;
        }
        float ss = 0.f;
        bf16x8 sv;
        #pragma unroll
        for (int i = 0; i < 8; ++i) {
          unsigned int u = __float_as_uint(v[i]);
          u = (u + 0x7fffu + ((u >> 16) & 1u)) & 0xffff0000u;
          float vb = __uint_as_float(u);
          ss += vb * vb;
          sv[i] = (short)(u >> 16);
        }
        const int idx = (jl * NC + cb) ^ ((jl & 7) << 3);
        *reinterpret_cast<bf16x8*>(&b_s[idx]) = sv;
        scr[jl][cg] = ss;
      }
    }
    __syncthreads();
    if (t < 80) {
      float s = 0.f;
      #pragma unroll
      for (int i = 0; i < 16; ++i) s += scr[t][i];
      invn2_s[t] = 1.f / fmaxf(sqrtf(s), 1e-12f);
    }
    __syncthreads();
    {
      const int m = wave;
      const int q = lane >> 4;
      const int n = lane & 15;
      f32x4 acc0 = {0.f, 0.f, 0.f, 0.f};
      f32x4 acc1 = {0.f, 0.f, 0.f, 0.f};
      const int wl  = m * 16 + n;
      const int jl0 = m * 16 + n;
      const int jl1 = m * 16 + 16 + n;
      #pragma unroll
      for (int kk = 0; kk < 4; ++kk) {
        const int c0 = kk * 32 + q * 8;
        bf16x8 avv = *reinterpret_cast<const bf16x8*>(&a_s[(wl  * NC + c0) ^ ((wl  & 7) << 3)]);
        bf16x8 bv0 = *reinterpret_cast<const bf16x8*>(&b_s[(jl0 * NC + c0) ^ ((jl0 & 7) << 3)]);
        bf16x8 bv1 = *reinterpret_cast<const bf16x8*>(&b_s[(jl1 * NC + c0) ^ ((jl1 & 7) << 3)]);
        acc0 = __builtin_amdgcn_mfma_f32_16x16x32_bf16(avv, bv0, acc0, 0, 0, 0);
        acc1 = __builtin_amdgcn_mfma_f32_16x16x32_bf16(avv, bv1, acc1, 0, 0, 0);
      }
      #pragma unroll
      for (int T = 0; T < 2; ++T) {
        const f32x4 a = T ? acc1 : acc0;
        const int jl = m * 16 + T * 16 + n;
        const float i2 = invn2_s[jl];
        #pragma unroll
        for (int r = 0; r < 4; ++r) {
          const int wr = m * 16 + q * 4 + r;
          const int dx = wr + 4 - jl;
          if (dx >= -4 && dx <= 4) {
            out_s[dx + 4][wr] = a[r] * invn1_s[wr] * i2;
          }
        }
      }
    }
    __syncthreads();
    #pragma unroll
    for (int kidx = 0; kidx < 3; ++kidx) {
      const int k = kidx * 256 + t;
      if (k < 9 * 64) {
        const int dx = k >> 6;
        const int wl = k & 63;
        const int d  = dyi * 9 + dx;
        out[(((size_t)b * 81 + d) * NH + h) * NW + w0 + wl] = out_s[dx][wl];
      }
    }
  }
}

extern "C" void kernel_launch(void* const* d_in, const int* in_sizes, int n_in,
                              void* d_out, int out_size, void* d_ws, size_t ws_size,
                              hipStream_t stream) {
  const float* f1 = (const float*)d_in[0];
  const float* f2 = (const float*)d_in[1];
  float* out = (float*)d_out;
  if (d_ws != nullptr && ws_size >= WS_NEEDED) {
    unsigned short* fn = (unsigned short*)d_ws;
    normalize_hwc<<<dim3(NPIX / 256, 2), 256, 0, stream>>>(f1, f2, fn);
    corr_hwc2<<<dim3(920), 128, 0, stream>>>(fn, out);
  } else {
    corr_mfma<<<dim3(5, NH, NB), 256, 0, stream>>>(f1, f2, out);
  }
}

// Round 7
// 132.979 us; speedup vs baseline: 1.6085x; 1.0789x over previous
//
#include <hip/hip_runtime.h>

#define NB 4
#define NC 128
#define NH 184
#define NW 320
#define TH 8                                      // K2: output h-rows per block
#define TWB 32                                    // K2: output w-cols per block
#define HWPIX (NH * NW)                           // 58880
#define NPIX (NB * NH * NW)                       // 235520 pixels per tensor
#define ZOFF ((size_t)2 * NPIX * NC)              // zero page offset (shorts)
#define WS_NEEDED (ZOFF * 2 + 512)                // 120.6 MB bf16 + zero page

typedef __attribute__((ext_vector_type(8))) short bf16x8;
typedef __attribute__((ext_vector_type(4))) float f32x4;

__device__ __forceinline__ unsigned short f2bf(float f) {
  unsigned int u = __float_as_uint(f);
  u = u + 0x7fffu + ((u >> 16) & 1u);             // RNE
  return (unsigned short)(u >> 16);
}

// ========== K1: normalize + CHW->HWC + fp32->bf16 ==========
// 64 pixels x 128 channels per block; thread = 4 pixels x 8 channels
// (v[8] = 32 data VGPRs -> no spill; R6's v[32]=128 spilled at VGPR=76)
__global__ __launch_bounds__(256) void normalize_hwc(const float* __restrict__ f1,
                                                     const float* __restrict__ f2,
                                                     unsigned short* __restrict__ fn) {
  const int t  = threadIdx.x;
  const int qd = t & 15;                  // pixel-quad 0..15 (4 consecutive pixels)
  const int cg = t >> 4;                  // channel group 0..15: [cg*8, cg*8+8)
  const int tensor = blockIdx.y;
  const float* src = tensor ? f2 : f1;
  unsigned short* dst = fn + (tensor ? (size_t)NPIX * NC : 0);

  const int p0  = blockIdx.x * 64;        // flat pixel base (b uniform: 58880=920*64)
  const int b   = blockIdx.x / 920;       // 920 blocks per image
  const int hw0 = (blockIdx.x - b * 920) * 64;

  __shared__ f32x4 scr[16][16];           // [cg][qd] sumsq partials
  __shared__ f32x4 invq[16];              // per-quad inverse norms (4 pixels each)

  const float* sp = src + ((size_t)b * NC + cg * 8) * HWPIX + hw0 + qd * 4;
  f32x4 v[8];
  f32x4 ssv = {0.f, 0.f, 0.f, 0.f};
  #pragma unroll
  for (int i = 0; i < 8; ++i) {           // 16 lanes x 16B = 256B segments
    v[i] = *reinterpret_cast<const f32x4*>(sp + (size_t)i * HWPIX);
    ssv += v[i] * v[i];
  }
  scr[cg][qd] = ssv;
  __syncthreads();
  if (t < 16) {
    f32x4 s = scr[0][t];
    #pragma unroll
    for (int g = 1; g < 16; ++g) s += scr[g][t];
    f32x4 iv;
    #pragma unroll
    for (int px = 0; px < 4; ++px) iv[px] = 1.f / fmaxf(sqrtf(s[px]), 1e-12f);
    invq[t] = iv;
  }
  __syncthreads();
  const f32x4 iv = invq[qd];

  unsigned short* dp = dst + ((size_t)p0 + qd * 4) * NC + cg * 8;
  #pragma unroll
  for (int px = 0; px < 4; ++px) {
    bf16x8 sv;
    #pragma unroll
    for (int j = 0; j < 8; ++j) sv[j] = (short)f2bf(v[j][px] * iv[px]);
    *reinterpret_cast<bf16x8*>(dp + (size_t)px * NC) = sv;   // cg 0..3 fill a 64B line
  }
  // zero page for K2's OOB loads (same-stream ordering)
  if (blockIdx.x == 0 && tensor == 0 && t < 128) fn[ZOFF + t] = 0;
}

// ========== K2: vertical-tiled banded MFMA; f2 rows streamed once ==========
__global__ __launch_bounds__(128, 2) void corr_hwc2(const unsigned short* __restrict__ fn,
                                                    float* __restrict__ out) {
  // grid 920 = 8*115; ht-major so same-XCD neighbors share f2 rows in L2
  const int bid = blockIdx.x;
  const int swz = (bid & 7) * 115 + (bid >> 3);
  const int ht  = swz % 23;
  const int wtb = (swz / 23) % 10;
  const int b   = swz / 230;
  const int h0  = ht * TH;
  const int w0  = wtb * TWB;

  const int t = threadIdx.x;                      // 0..127 (2 waves)
  const int lane = t & 63;
  const int wv = t >> 6;                          // wave owns w in [wv*16, wv*16+16)
  const int q = lane >> 4;
  const int n = lane & 15;

  const unsigned short* f1n = fn;
  const unsigned short* f2n = fn + (size_t)NPIX * NC;
  const unsigned short* zpage = fn + ZOFF;

  __shared__ float out_s[2][9][17];               // per-wave transpose buffer

  // ---- A fragments: 8 rows x 4 kk, loaded once, reused for all 81 disps ----
  bf16x8 av[TH][4];
  #pragma unroll
  for (int hh = 0; hh < TH; ++hh) {
    const unsigned short* ap =
        f1n + ((size_t)(b * NH + h0 + hh) * NW + w0 + wv * 16 + n) * NC + q * 8;
    #pragma unroll
    for (int kk = 0; kk < 4; ++kk)
      av[hh][kk] = *reinterpret_cast<const bf16x8*>(ap + kk * 32);
  }

  const int j0 = w0 + wv * 16 - 4 + n;            // N-tile 0 col (may be <0)
  const int j1 = j0 + 16;                         // N-tile 1 col (may be >=NW)

  bf16x8 bA[2][4], bB[2][4];

#define LD_ROW(BUF, RR) do {                                                     \
    const int hr_ = h0 + (RR);                                                   \
    const bool rok_ = (hr_ >= 0) && (hr_ < NH);                                  \
    const size_t rb_ = (size_t)(b * NH + (rok_ ? hr_ : 0)) * NW * NC;            \
    const unsigned short* p0_ =                                                  \
        (rok_ && j0 >= 0) ? (f2n + rb_ + (size_t)j0 * NC + q * 8) : (zpage + q * 8); \
    const unsigned short* p1_ =                                                  \
        (rok_ && j1 < NW) ? (f2n + rb_ + (size_t)j1 * NC + q * 8) : (zpage + q * 8); \
    _Pragma("unroll")                                                            \
    for (int kk = 0; kk < 4; ++kk)                                               \
      BUF[0][kk] = *reinterpret_cast<const bf16x8*>(p0_ + kk * 32);              \
    _Pragma("unroll")                                                            \
    for (int kk = 0; kk < 4; ++kk)                                               \
      BUF[1][kk] = *reinterpret_cast<const bf16x8*>(p1_ + kk * 32);              \
  } while (0)

#define COMPUTE(BUF, RR) do {                                                    \
    _Pragma("unroll")                                                            \
    for (int hh = 0; hh < TH; ++hh) {                                            \
      const int dyi_ = hh - (RR) + 4;             /* dy+4; wave-uniform */       \
      if (dyi_ >= 0 && dyi_ <= 8) {                                              \
        f32x4 a0 = {0.f, 0.f, 0.f, 0.f};                                         \
        f32x4 a1 = {0.f, 0.f, 0.f, 0.f};                                         \
        _Pragma("unroll")                                                        \
        for (int kk = 0; kk < 4; ++kk) {                                         \
          a0 = __builtin_amdgcn_mfma_f32_16x16x32_bf16(av[hh][kk], BUF[0][kk], a0, 0, 0, 0); \
          a1 = __builtin_amdgcn_mfma_f32_16x16x32_bf16(av[hh][kk], BUF[1][kk], a1, 0, 0, 0); \
        }                                                                        \
        _Pragma("unroll")                                                        \
        for (int r = 0; r < 4; ++r) {            /* T=0: dxi = 4q+r+8-n  */      \
          const int dxi0 = 4 * q + r + 8 - n;                                    \
          if (dxi0 >= 0 && dxi0 <= 8) out_s[wv][dxi0][4 * q + r] = a0[r];        \
          const int dxi1 = 4 * q + r - 8 - n;    /* T=1 */                       \
          if (dxi1 >= 0 && dxi1 <= 8) out_s[wv][dxi1][4 * q + r] = a1[r];        \
        }                                                                        \
        _Pragma("unroll")                                                        \
        for (int i = 0; i < 3; ++i) {                                            \
          const int idx = i * 64 + lane;                                         \
          if (idx < 144) {                                                       \
            const int dx_ = idx >> 4;                                            \
            const int wc_ = idx & 15;                                            \
            out[((size_t)(b * 81 + dyi_ * 9 + dx_) * NH + (h0 + hh)) * NW        \
                + w0 + wv * 16 + wc_] = out_s[wv][dx_][wc_];                     \
          }                                                                      \
        }                                                                        \
      }                                                                          \
    }                                                                            \
  } while (0)

  // ---- main loop over 16 f2 rows (rr = hr - h0 in [-4, 11]), double-buffered ----
  LD_ROW(bA, -4);
  for (int k = 0; k < 7; ++k) {
    const int rr = 2 * k - 4;
    LD_ROW(bB, rr + 1);
    __builtin_amdgcn_sched_barrier(0);
    COMPUTE(bA, rr);
    LD_ROW(bA, rr + 2);
    __builtin_amdgcn_sched_barrier(0);
    COMPUTE(bB, rr + 1);
  }
  LD_ROW(bB, 11);
  __builtin_amdgcn_sched_barrier(0);
  COMPUTE(bA, 10);
  COMPUTE(bB, 11);

#undef LD_ROW
#undef COMPUTE
}

// ========== fallback: round-2 fused kernel (used if ws too small) ==========
__global__ __launch_bounds__(256) void corr_mfma(const float* __restrict__ f1,
                                                 const float* __restrict__ f2,
                                                 float* __restrict__ out) {
  const int wt = blockIdx.x;
  const int h  = blockIdx.y;
  const int b  = blockIdx.z;
  const int w0 = wt * 64;
  const int t  = threadIdx.x;
  const int lane = t & 63;
  const int wave = t >> 6;

  __shared__ __align__(16) unsigned short a_s[64 * NC];
  __shared__ __align__(16) unsigned short b_s[80 * NC];
  __shared__ float scr[80][17];
  __shared__ float invn1_s[64];
  __shared__ float invn2_s[80];
  __shared__ float out_s[9][64];

  const size_t HW = (size_t)NH * NW;

  {
    const int w  = t & 63;
    const int cg = t >> 6;
    float ss = 0.f;
    #pragma unroll
    for (int cc = 0; cc < 4; ++cc) {
      const int cb = cg * 32 + cc * 8;
      const float* p = f1 + ((size_t)b * NC + cb) * HW + (size_t)h * NW + w0 + w;
      float v[8];
      #pragma unroll
      for (int i = 0; i < 8; ++i) v[i] = p[i * HW];
      bf16x8 sv;
      #pragma unroll
      for (int i = 0; i < 8; ++i) {
        unsigned int u = __float_as_uint(v[i]);
        u = (u + 0x7fffu + ((u >> 16) & 1u)) & 0xffff0000u;
        float vb = __uint_as_float(u);
        ss += vb * vb;
        sv[i] = (short)(u >> 16);
      }
      const int idx = (w * NC + cb) ^ ((w & 7) << 3);
      *reinterpret_cast<bf16x8*>(&a_s[idx]) = sv;
    }
    scr[w][cg] = ss;
  }
  __syncthreads();
  if (t < 64) {
    float s = scr[t][0] + scr[t][1] + scr[t][2] + scr[t][3];
    invn1_s[t] = 1.f / fmaxf(sqrtf(s), 1e-12f);
  }

  for (int dyi = 0; dyi < 9; ++dyi) {
    __syncthreads();
    const int hr = h + 4 - dyi;
    {
      const int jl16 = t & 15;
      const int cg   = t >> 4;
      const int cb   = cg * 8;
      const bool rowok = (hr >= 0) && (hr < NH);
      #pragma unroll
      for (int s5 = 0; s5 < 5; ++s5) {
        const int jl = s5 * 16 + jl16;
        const int jg = w0 - 4 + jl;
        float v[8];
        if (rowok && jg >= 0 && jg < NW) {
          const float* p = f2 + ((size_t)b * NC + cb) * HW + (size_t)hr * NW + jg;
          #pragma unroll
          for (int i = 0; i < 8; ++i) v[i] = p[i * HW];
        } else {
          #pragma unroll
          for (int i = 0; i < 8; ++i) v[i] = 0.f;
        }
        float ss = 0.f;
        bf16x8 sv;
        #pragma unroll
        for (int i = 0; i < 8; ++i) {
          unsigned int u = __float_as_uint(v[i]);
          u = (u + 0x7fffu + ((u >> 16) & 1u)) & 0xffff0000u;
          float vb = __uint_as_float(u);
          ss += vb * vb;
          sv[i] = (short)(u >> 16);
        }
        const int idx = (jl * NC + cb) ^ ((jl & 7) << 3);
        *reinterpret_cast<bf16x8*>(&b_s[idx]) = sv;
        scr[jl][cg] = ss;
      }
    }
    __syncthreads();
    if (t < 80) {
      float s = 0.f;
      #pragma unroll
      for (int i = 0; i < 16; ++i) s += scr[t][i];
      invn2_s[t] = 1.f / fmaxf(sqrtf(s), 1e-12f);
    }
    __syncthreads();
    {
      const int m = wave;
      const int q = lane >> 4;
      const int n = lane & 15;
      f32x4 acc0 = {0.f, 0.f, 0.f, 0.f};
      f32x4 acc1 = {0.f, 0.f, 0.f, 0.f};
      const int wl  = m * 16 + n;
      const int jl0 = m * 16 + n;
      const int jl1 = m * 16 + 16 + n;
      #pragma unroll
      for (int kk = 0; kk < 4; ++kk) {
        const int c0 = kk * 32 + q * 8;
        bf16x8 avv = *reinterpret_cast<const bf16x8*>(&a_s[(wl  * NC + c0) ^ ((wl  & 7) << 3)]);
        bf16x8 bv0 = *reinterpret_cast<const bf16x8*>(&b_s[(jl0 * NC + c0) ^ ((jl0 & 7) << 3)]);
        bf16x8 bv1 = *reinterpret_cast<const bf16x8*>(&b_s[(jl1 * NC + c0) ^ ((jl1 & 7) << 3)]);
        acc0 = __builtin_amdgcn_mfma_f32_16x16x32_bf16(avv, bv0, acc0, 0, 0, 0);
        acc1 = __builtin_amdgcn_mfma_f32_16x16x32_bf16(avv, bv1, acc1, 0, 0, 0);
      }
      #pragma unroll
      for (int T = 0; T < 2; ++T) {
        const f32x4 a = T ? acc1 : acc0;
        const int jl = m * 16 + T * 16 + n;
        const float i2 = invn2_s[jl];
        #pragma unroll
        for (int r = 0; r < 4; ++r) {
          const int wr = m * 16 + q * 4 + r;
          const int dx = wr + 4 - jl;
          if (dx >= -4 && dx <= 4) {
            out_s[dx + 4][wr] = a[r] * invn1_s[wr] * i2;
          }
        }
      }
    }
    __syncthreads();
    #pragma unroll
    for (int kidx = 0; kidx < 3; ++kidx) {
      const int k = kidx * 256 + t;
      if (k < 9 * 64) {
        const int dx = k >> 6;
        const int wl = k & 63;
        const int d  = dyi * 9 + dx;
        out[(((size_t)b * 81 + d) * NH + h) * NW + w0 + wl] = out_s[dx][wl];
      }
    }
  }
}

extern "C" void kernel_launch(void* const* d_in, const int* in_sizes, int n_in,
                              void* d_out, int out_size, void* d_ws, size_t ws_size,
                              hipStream_t stream) {
  const float* f1 = (const float*)d_in[0];
  const float* f2 = (const float*)d_in[1];
  float* out = (float*)d_out;
  if (d_ws != nullptr && ws_size >= WS_NEEDED) {
    unsigned short* fn = (unsigned short*)d_ws;
    normalize_hwc<<<dim3(NPIX / 64, 2), 256, 0, stream>>>(f1, f2, fn);
    corr_hwc2<<<dim3(920), 128, 0, stream>>>(fn, out);
  } else {
    corr_mfma<<<dim3(5, NH, NB), 256, 0, stream>>>(f1, f2, out);
  }
}

// Round 8
// 132.969 us; speedup vs baseline: 1.6086x; 1.0001x over previous
//
#include <hip/hip_runtime.h>

#define NB 4
#define NC 128
#define NH 184
#define NW 320
#define TH 8                                      // K2: output h-rows per block
#define TWB 32                                    // K2: output w-cols per block
#define HWPIX (NH * NW)                           // 58880
#define NPIX (NB * NH * NW)                       // 235520 pixels per tensor
#define ZOFF ((size_t)2 * NPIX * NC)              // zero page offset (shorts)
#define WS_NEEDED (ZOFF * 2 + 512)                // 120.6 MB bf16 + zero page

typedef __attribute__((ext_vector_type(8))) short bf16x8;
typedef __attribute__((ext_vector_type(4))) float f32x4;

__device__ __forceinline__ unsigned short f2bf(float f) {
  unsigned int u = __float_as_uint(f);
  u = u + 0x7fffu + ((u >> 16) & 1u);             // RNE
  return (unsigned short)(u >> 16);
}

// ========== K1: normalize + CHW->HWC + fp32->bf16, LDS-tiled transpose ==========
// block = 256 consecutive pixels x 128 channels. BOTH global sides are
// 1KB-contiguous per instruction (R7's 256B/64B scatter ran at 3.5 TB/s).
// LDS tile swizzle: cb' = (cb + (p>>2) + 4*(p&3)) & 15 -> bank-floor both phases.
__global__ __launch_bounds__(256) void normalize_hwc(const float* __restrict__ f1,
                                                     const float* __restrict__ f2,
                                                     unsigned short* __restrict__ fn) {
  const int t = threadIdx.x;
  const int tensor = blockIdx.y;
  const float* src = tensor ? f2 : f1;
  unsigned short* dst = fn + (tensor ? (size_t)NPIX * NC : 0);

  const int p0 = blockIdx.x * 256;        // flat pixel base (920 blocks/tensor)
  const int b  = blockIdx.x / 230;        // 230 blocks per image (58880/256)
  const int hw0 = (blockIdx.x - b * 230) * 256;

  __shared__ __align__(16) unsigned short tile[256 * 128];  // 64 KB, [p][cb'] swizzled
  __shared__ f32x4 scr[4][64];
  __shared__ float invq[256];

  const int wv = t >> 6;                  // wave id 0..3
  const int l6 = t & 63;                  // lane

  // ---- phase 1: 1KB-coalesced channel-row loads -> bf16 -> swizzled LDS ----
  f32x4 ssv = {0.f, 0.f, 0.f, 0.f};
  #pragma unroll
  for (int chunk = 0; chunk < 4; ++chunk) {
    const int cb = chunk * 4 + wv;        // channel block: channels [cb*8, cb*8+8)
    const float* sp = src + ((size_t)b * NC + cb * 8) * HWPIX + hw0 + l6 * 4;
    f32x4 v[8];
    #pragma unroll
    for (int i = 0; i < 8; ++i)           // 64 lanes x 16B = 1KB contiguous, aligned
      v[i] = *reinterpret_cast<const f32x4*>(sp + (size_t)i * HWPIX);
    #pragma unroll
    for (int px = 0; px < 4; ++px) {
      bf16x8 sv;
      #pragma unroll
      for (int i = 0; i < 8; ++i) {
        unsigned int u = __float_as_uint(v[i][px]);
        u = (u + 0x7fffu + ((u >> 16) & 1u)) & 0xffff0000u;   // RNE to bf16
        float vb = __uint_as_float(u);
        ssv[px] += vb * vb;               // norm of the bf16-rounded vector
        sv[i] = (short)(u >> 16);
      }
      const int p   = l6 * 4 + px;        // tile-local pixel
      const int cbs = (cb + l6 + px * 4) & 15;                // = (cb + (p>>2) + 4*(p&3)) & 15
      *reinterpret_cast<bf16x8*>(&tile[p * 128 + cbs * 8]) = sv;
    }
  }
  scr[wv][l6] = ssv;
  __syncthreads();
  if (t < 64) {
    f32x4 s = scr[0][t] + scr[1][t] + scr[2][t] + scr[3][t];
    #pragma unroll
    for (int px = 0; px < 4; ++px)
      invq[t * 4 + px] = 1.f / fmaxf(sqrtf(s[px]), 1e-12f);
  }
  __syncthreads();

  // ---- phase 2: swizzled LDS read -> scale -> 1KB-coalesced HWC store ----
  const int m = t & 15;                   // channel block on the read side
  #pragma unroll
  for (int i = 0; i < 16; ++i) {
    const int p   = i * 16 + (t >> 4);
    const int cbs = (m + i * 4 + (t >> 6) + 4 * ((t >> 4) & 3)) & 15;  // same swizzle fn
    bf16x8 raw = *reinterpret_cast<const bf16x8*>(&tile[p * 128 + cbs * 8]);
    const float inv = invq[p];
    bf16x8 sv;
    #pragma unroll
    for (int j = 0; j < 8; ++j) {
      float x = __uint_as_float(((unsigned int)(unsigned short)raw[j]) << 16);
      sv[j] = (short)f2bf(x * inv);
    }
    *reinterpret_cast<bf16x8*>(dst + (size_t)(p0 + p) * NC + m * 8) = sv;  // 1KB/instr
  }
  // zero page for K2's OOB loads (same-stream ordering)
  if (blockIdx.x == 0 && tensor == 0 && t < 128) fn[ZOFF + t] = 0;
}

// ========== K2: vertical-tiled banded MFMA; f2 rows streamed once (UNCHANGED) ==========
__global__ __launch_bounds__(128, 2) void corr_hwc2(const unsigned short* __restrict__ fn,
                                                    float* __restrict__ out) {
  // grid 920 = 8*115; ht-major so same-XCD neighbors share f2 rows in L2
  const int bid = blockIdx.x;
  const int swz = (bid & 7) * 115 + (bid >> 3);
  const int ht  = swz % 23;
  const int wtb = (swz / 23) % 10;
  const int b   = swz / 230;
  const int h0  = ht * TH;
  const int w0  = wtb * TWB;

  const int t = threadIdx.x;                      // 0..127 (2 waves)
  const int lane = t & 63;
  const int wv = t >> 6;                          // wave owns w in [wv*16, wv*16+16)
  const int q = lane >> 4;
  const int n = lane & 15;

  const unsigned short* f1n = fn;
  const unsigned short* f2n = fn + (size_t)NPIX * NC;
  const unsigned short* zpage = fn + ZOFF;

  __shared__ float out_s[2][9][17];               // per-wave transpose buffer

  // ---- A fragments: 8 rows x 4 kk, loaded once, reused for all 81 disps ----
  bf16x8 av[TH][4];
  #pragma unroll
  for (int hh = 0; hh < TH; ++hh) {
    const unsigned short* ap =
        f1n + ((size_t)(b * NH + h0 + hh) * NW + w0 + wv * 16 + n) * NC + q * 8;
    #pragma unroll
    for (int kk = 0; kk < 4; ++kk)
      av[hh][kk] = *reinterpret_cast<const bf16x8*>(ap + kk * 32);
  }

  const int j0 = w0 + wv * 16 - 4 + n;            // N-tile 0 col (may be <0)
  const int j1 = j0 + 16;                         // N-tile 1 col (may be >=NW)

  bf16x8 bA[2][4], bB[2][4];

#define LD_ROW(BUF, RR) do {                                                     \
    const int hr_ = h0 + (RR);                                                   \
    const bool rok_ = (hr_ >= 0) && (hr_ < NH);                                  \
    const size_t rb_ = (size_t)(b * NH + (rok_ ? hr_ : 0)) * NW * NC;            \
    const unsigned short* p0_ =                                                  \
        (rok_ && j0 >= 0) ? (f2n + rb_ + (size_t)j0 * NC + q * 8) : (zpage + q * 8); \
    const unsigned short* p1_ =                                                  \
        (rok_ && j1 < NW) ? (f2n + rb_ + (size_t)j1 * NC + q * 8) : (zpage + q * 8); \
    _Pragma("unroll")                                                            \
    for (int kk = 0; kk < 4; ++kk)                                               \
      BUF[0][kk] = *reinterpret_cast<const bf16x8*>(p0_ + kk * 32);              \
    _Pragma("unroll")                                                            \
    for (int kk = 0; kk < 4; ++kk)                                               \
      BUF[1][kk] = *reinterpret_cast<const bf16x8*>(p1_ + kk * 32);              \
  } while (0)

#define COMPUTE(BUF, RR) do {                                                    \
    _Pragma("unroll")                                                            \
    for (int hh = 0; hh < TH; ++hh) {                                            \
      const int dyi_ = hh - (RR) + 4;             /* dy+4; wave-uniform */       \
      if (dyi_ >= 0 && dyi_ <= 8) {                                              \
        f32x4 a0 = {0.f, 0.f, 0.f, 0.f};                                         \
        f32x4 a1 = {0.f, 0.f, 0.f, 0.f};                                         \
        _Pragma("unroll")                                                        \
        for (int kk = 0; kk < 4; ++kk) {                                         \
          a0 = __builtin_amdgcn_mfma_f32_16x16x32_bf16(av[hh][kk], BUF[0][kk], a0, 0, 0, 0); \
          a1 = __builtin_amdgcn_mfma_f32_16x16x32_bf16(av[hh][kk], BUF[1][kk], a1, 0, 0, 0); \
        }                                                                        \
        _Pragma("unroll")                                                        \
        for (int r = 0; r < 4; ++r) {            /* T=0: dxi = 4q+r+8-n  */      \
          const int dxi0 = 4 * q + r + 8 - n;                                    \
          if (dxi0 >= 0 && dxi0 <= 8) out_s[wv][dxi0][4 * q + r] = a0[r];        \
          const int dxi1 = 4 * q + r - 8 - n;    /* T=1 */                       \
          if (dxi1 >= 0 && dxi1 <= 8) out_s[wv][dxi1][4 * q + r] = a1[r];        \
        }                                                                        \
        _Pragma("unroll")                                                        \
        for (int i = 0; i < 3; ++i) {                                            \
          const int idx = i * 64 + lane;                                         \
          if (idx < 144) {                                                       \
            const int dx_ = idx >> 4;                                            \
            const int wc_ = idx & 15;                                            \
            out[((size_t)(b * 81 + dyi_ * 9 + dx_) * NH + (h0 + hh)) * NW        \
                + w0 + wv * 16 + wc_] = out_s[wv][dx_][wc_];                     \
          }                                                                      \
        }                                                                        \
      }                                                                          \
    }                                                                            \
  } while (0)

  // ---- main loop over 16 f2 rows (rr = hr - h0 in [-4, 11]), double-buffered ----
  LD_ROW(bA, -4);
  for (int k = 0; k < 7; ++k) {
    const int rr = 2 * k - 4;
    LD_ROW(bB, rr + 1);
    __builtin_amdgcn_sched_barrier(0);
    COMPUTE(bA, rr);
    LD_ROW(bA, rr + 2);
    __builtin_amdgcn_sched_barrier(0);
    COMPUTE(bB, rr + 1);
  }
  LD_ROW(bB, 11);
  __builtin_amdgcn_sched_barrier(0);
  COMPUTE(bA, 10);
  COMPUTE(bB, 11);

#undef LD_ROW
#undef COMPUTE
}

// ========== fallback: round-2 fused kernel (used if ws too small) ==========
__global__ __launch_bounds__(256) void corr_mfma(const float* __restrict__ f1,
                                                 const float* __restrict__ f2,
                                                 float* __restrict__ out) {
  const int wt = blockIdx.x;
  const int h  = blockIdx.y;
  const int b  = blockIdx.z;
  const int w0 = wt * 64;
  const int t  = threadIdx.x;
  const int lane = t & 63;
  const int wave = t >> 6;

  __shared__ __align__(16) unsigned short a_s[64 * NC];
  __shared__ __align__(16) unsigned short b_s[80 * NC];
  __shared__ float scr[80][17];
  __shared__ float invn1_s[64];
  __shared__ float invn2_s[80];
  __shared__ float out_s[9][64];

  const size_t HW = (size_t)NH * NW;

  {
    const int w  = t & 63;
    const int cg = t >> 6;
    float ss = 0.f;
    #pragma unroll
    for (int cc = 0; cc < 4; ++cc) {
      const int cb = cg * 32 + cc * 8;
      const float* p = f1 + ((size_t)b * NC + cb) * HW + (size_t)h * NW + w0 + w;
      float v[8];
      #pragma unroll
      for (int i = 0; i < 8; ++i) v[i] = p[i * HW];
      bf16x8 sv;
      #pragma unroll
      for (int i = 0; i < 8; ++i) {
        unsigned int u = __float_as_uint(v[i]);
        u = (u + 0x7fffu + ((u >> 16) & 1u)) & 0xffff0000u;
        float vb = __uint_as_float(u);
        ss += vb * vb;
        sv[i] = (short)(u >> 16);
      }
      const int idx = (w * NC + cb) ^ ((w & 7) << 3);
      *reinterpret_cast<bf16x8*>(&a_s[idx]) = sv;
    }
    scr[w][cg] = ss;
  }
  __syncthreads();
  if (t < 64) {
    float s = scr[t][0] + scr[t][1] + scr[t][2] + scr[t][3];
    invn1_s[t] = 1.f / fmaxf(sqrtf(s), 1e-12f);
  }

  for (int dyi = 0; dyi < 9; ++dyi) {
    __syncthreads();
    const int hr = h + 4 - dyi;
    {
      const int jl16 = t & 15;
      const int cg   = t >> 4;
      const int cb   = cg * 8;
      const bool rowok = (hr >= 0) && (hr < NH);
      #pragma unroll
      for (int s5 = 0; s5 < 5; ++s5) {
        const int jl = s5 * 16 + jl16;
        const int jg = w0 - 4 + jl;
        float v[8];
        if (rowok && jg >= 0 && jg < NW) {
          const float* p = f2 + ((size_t)b * NC + cb) * HW + (size_t)hr * NW + jg;
          #pragma unroll
          for (int i = 0; i < 8; ++i) v[i] = p[i * HW];
        } else {
          #pragma unroll
          for (int i = 0; i < 8; ++i) v[i] = 0.f;
        }
        float ss = 0.f;
        bf16x8 sv;
        #pragma unroll
        for (int i = 0; i < 8; ++i) {
          unsigned int u = __float_as_uint(v[i]);
          u = (u + 0x7fffu + ((u >> 16) & 1u)) & 0xffff0000u;
          float vb = __uint_as_float(u);
          ss += vb * vb;
          sv[i] = (short)(u >> 16);
        }
        const int idx = (jl * NC + cb) ^ ((jl & 7) << 3);
        *reinterpret_cast<bf16x8*>(&b_s[idx]) = sv;
        scr[jl][cg] = ss;
      }
    }
    __syncthreads();
    if (t < 80) {
      float s = 0.f;
      #pragma unroll
      for (int i = 0; i < 16; ++i) s += scr[t][i];
      invn2_s[t] = 1.f / fmaxf(sqrtf(s), 1e-12f);
    }
    __syncthreads();
    {
      const int m = wave;
      const int q = lane >> 4;
      const int n = lane & 15;
      f32x4 acc0 = {0.f, 0.f, 0.f, 0.f};
      f32x4 acc1 = {0.f, 0.f, 0.f, 0.f};
      const int wl  = m * 16 + n;
      const int jl0 = m * 16 + n;
      const int jl1 = m * 16 + 16 + n;
      #pragma unroll
      for (int kk = 0; kk < 4; ++kk) {
        const int c0 = kk * 32 + q * 8;
        bf16x8 avv = *reinterpret_cast<const bf16x8*>(&a_s[(wl  * NC + c0) ^ ((wl  & 7) << 3)]);
        bf16x8 bv0 = *reinterpret_cast<const bf16x8*>(&b_s[(jl0 * NC + c0) ^ ((jl0 & 7) << 3)]);
        bf16x8 bv1 = *reinterpret_cast<const bf16x8*>(&b_s[(jl1 * NC + c0) ^ ((jl1 & 7) << 3)]);
        acc0 = __builtin_amdgcn_mfma_f32_16x16x32_bf16(avv, bv0, acc0, 0, 0, 0);
        acc1 = __builtin_amdgcn_mfma_f32_16x16x32_bf16(avv, bv1, acc1, 0, 0, 0);
      }
      #pragma unroll
      for (int T = 0; T < 2; ++T) {
        const f32x4 a = T ? acc1 : acc0;
        const int jl = m * 16 + T * 16 + n;
        const float i2 = invn2_s[jl];
        #pragma unroll
        for (int r = 0; r < 4; ++r) {
          const int wr = m * 16 + q * 4 + r;
          const int dx = wr + 4 - jl;
          if (dx >= -4 && dx <= 4) {
            out_s[dx + 4][wr] = a[r] * invn1_s[wr] * i2;
          }
        }
      }
    }
    __syncthreads();
    #pragma unroll
    for (int kidx = 0; kidx < 3; ++kidx) {
      const int k = kidx * 256 + t;
      if (k < 9 * 64) {
        const int dx = k >> 6;
        const int wl = k & 63;
        const int d  = dyi * 9 + dx;
        out[(((size_t)b * 81 + d) * NH + h) * NW + w0 + wl] = out_s[dx][wl];
      }
    }
  }
}

extern "C" void kernel_launch(void* const* d_in, const int* in_sizes, int n_in,
                              void* d_out, int out_size, void* d_ws, size_t ws_size,
                              hipStream_t stream) {
  const float* f1 = (const float*)d_in[0];
  const float* f2 = (const float*)d_in[1];
  float* out = (float*)d_out;
  if (d_ws != nullptr && ws_size >= WS_NEEDED) {
    unsigned short* fn = (unsigned short*)d_ws;
    normalize_hwc<<<dim3(NPIX / 256, 2), 256, 0, stream>>>(f1, f2, fn);
    corr_hwc2<<<dim3(920), 128, 0, stream>>>(fn, out);
  } else {
    corr_mfma<<<dim3(5, NH, NB), 256, 0, stream>>>(f1, f2, out);
  }
}